// Round 1
// 869.275 us; speedup vs baseline: 1.0079x; 1.0079x over previous
//
#include <hip/hip_runtime.h>

// LightGCN: out = (x0 + A x0 + A^2 x0 + A^3 x0) / 4, COO 4M nnz, N=300k, D=64.
// R5: inter-layer activations stored in bf16 (row=128B) -> per-XCD compulsory
// gather traffic halves (FETCH was ~8 XCDs x |x|). Accumulation stays fp32.
// R6: SpMM edge fetch via wave-uniform SGPR loads (s_load) instead of
// lane-load + 2x ds_bpermute per edge. The bpermutes serialized on the
// per-CU LDS pipe (~78us of the 157us dispatch); scalar loads use the
// scalar cache and free that pipe entirely.
// Build pipeline as R4 (hist + scan + 2-phase bucket sort), buckets 1024.

#define NUSERS 200000
#define NITEMS 100000
#define NNODES 300000
#define DIM 64
#define NNZ_CNT 4000000

#define SCAN_CHUNK 1024
#define NCHUNKS ((NNODES + SCAN_CHUNK - 1) / SCAN_CHUNK)   // 293
#define CNT_PAD (NCHUNKS * SCAN_CHUNK)                     // 300032 ints (padded, zeros)

#define BSHIFT 10
#define BROWS  (1 << BSHIFT)                               // 1024 rows per bucket
#define NB     ((NNODES + BROWS - 1) >> BSHIFT)            // 293 buckets
#define EPB    8192                                        // edges per bucketA block

// ---------------- bf16 helpers (RNE) ----------------

__device__ __forceinline__ unsigned short f32_to_bf16(float f) {
    unsigned u = __float_as_uint(f);
    u += 0x7FFFu + ((u >> 16) & 1u);
    return (unsigned short)(u >> 16);
}
__device__ __forceinline__ float bf16_to_f32(unsigned short h) {
    return __uint_as_float(((unsigned)h) << 16);
}

// ---------------- CSR build: hist + scan ----------------

__global__ void k_hist(const int* __restrict__ rows, int* __restrict__ cnt) {
    int e = blockIdx.x * blockDim.x + threadIdx.x;
    if (e >= NNZ_CNT) return;
    atomicAdd(&cnt[rows[e]], 1);
}

__global__ void k_partial(const int* __restrict__ cnt, int* __restrict__ partial) {
    int t = threadIdx.x;
    int base = blockIdx.x * SCAN_CHUNK;
    int4 c = ((const int4*)(cnt + base))[t];
    int tsum = c.x + c.y + c.z + c.w;
    __shared__ int lds[256];
    lds[t] = tsum; __syncthreads();
    for (int d = 128; d > 0; d >>= 1) {
        if (t < d) lds[t] += lds[t + d];
        __syncthreads();
    }
    if (t == 0) partial[blockIdx.x] = lds[0];
}

__global__ void k_scanpartial(const int* __restrict__ partial, int* __restrict__ partoff) {
    int t = threadIdx.x;                     // 512 threads
    int v = (t < NCHUNKS) ? partial[t] : 0;
    __shared__ int lds[512];
    lds[t] = v; __syncthreads();
    for (int d = 1; d < 512; d <<= 1) {
        int cur = lds[t];
        int add = (t >= d) ? lds[t - d] : 0;
        __syncthreads();
        lds[t] = cur + add;
        __syncthreads();
    }
    if (t < NCHUNKS) partoff[t] = lds[t] - v;   // exclusive
}

__global__ void k_scan3(const int* __restrict__ cnt, const int* __restrict__ partoff,
                        int* __restrict__ rowptr) {
    int t = threadIdx.x, b = blockIdx.x;
    int base = b * SCAN_CHUNK;
    int4 c = ((const int4*)(cnt + base))[t];
    int tsum = c.x + c.y + c.z + c.w;
    __shared__ int lds[256];
    lds[t] = tsum; __syncthreads();
    for (int d = 1; d < 256; d <<= 1) {
        int cur = lds[t];
        int add = (t >= d) ? lds[t - d] : 0;
        __syncthreads();
        lds[t] = cur + add;
        __syncthreads();
    }
    int excl = lds[t] - tsum;
    int off = partoff[b] + excl;
    int idx = base + t * 4;
    rowptr[idx + 0] = off;
    rowptr[idx + 1] = off + c.x;
    rowptr[idx + 2] = off + c.x + c.y;
    rowptr[idx + 3] = off + c.x + c.y + c.z;
    // rowptr[NNODES] = NNZ emerges from zero-padded cnt.
}

// gcursor[b] = rowptr[min(b * BROWS, NNODES)]
__global__ void k_initcur(const int* __restrict__ rowptr, int* __restrict__ gcursor) {
    int t = blockIdx.x * blockDim.x + threadIdx.x;
    if (t >= NB) return;
    int r = t << BSHIFT;
    if (r > NNODES) r = NNODES;
    gcursor[t] = rowptr[r];
}

// ---------------- Phase A: bucket staging (LDS-binned) ----------------

__global__ void __launch_bounds__(256) k_bucketA(
        const int* __restrict__ rows, const int* __restrict__ cols,
        const float* __restrict__ vals, int* __restrict__ gcursor,
        int2* __restrict__ staged) {
    __shared__ int hist[NB];
    __shared__ int lbase[NB];
    __shared__ int lcur[NB];
    int t = threadIdx.x;
    int e0 = blockIdx.x * EPB;
    for (int i = t; i < NB; i += 256) { hist[i] = 0; lcur[i] = 0; }
    __syncthreads();
    // pass 1: local histogram
    for (int k = 0; k < EPB / 256; ++k) {
        int e = e0 + k * 256 + t;
        if (e < NNZ_CNT) atomicAdd(&hist[rows[e] >> BSHIFT], 1);
    }
    __syncthreads();
    // reserve contiguous ranges per bucket
    for (int i = t; i < NB; i += 256) {
        int h = hist[i];
        lbase[i] = h ? atomicAdd(&gcursor[i], h) : 0;
    }
    __syncthreads();
    // pass 2: place edges
    for (int k = 0; k < EPB / 256; ++k) {
        int e = e0 + k * 256 + t;
        if (e >= NNZ_CNT) continue;
        int r = rows[e];
        int b = r >> BSHIFT;
        int p = lbase[b] + atomicAdd(&lcur[b], 1);
        int2 rec;
        rec.x = ((r & (BROWS - 1)) << 19) | cols[e];   // rel_row[10] | col[19]
        rec.y = __float_as_int(vals[e]);
        staged[p] = rec;
    }
}

// ---------------- Phase B: per-bucket row sort (LDS cursors) ----------------

__global__ void __launch_bounds__(1024) k_bucketB(
        const int* __restrict__ rowptr, const int2* __restrict__ staged,
        int2* __restrict__ packed) {
    __shared__ int cur[BROWS];
    int b = blockIdx.x;
    int t = threadIdx.x;
    int r0 = b << BSHIFT;
    int r1 = min(r0 + BROWS, NNODES);
    int nrows = r1 - r0;
    for (int i = t; i < nrows; i += 1024) cur[i] = rowptr[r0 + i];
    __syncthreads();
    int start = rowptr[r0];
    int end   = rowptr[r1];
    for (int idx = start + t; idx < end; idx += 1024) {
        int2 rec = staged[idx];
        int rel = ((unsigned)rec.x) >> 19;
        int col = rec.x & 0x7FFFF;
        int pos = atomicAdd(&cur[rel], 1);
        int2 out; out.x = col; out.y = rec.y;
        packed[pos] = out;
    }
}

// ---------------- x0 -> bf16 + acc init ----------------

__global__ void k_init0(const float* __restrict__ ue, const float* __restrict__ ie,
                        unsigned short* __restrict__ xb0, float* __restrict__ acc) {
    int i = blockIdx.x * blockDim.x + threadIdx.x;      // float4 index
    const int total = NNODES * DIM / 4;
    if (i >= total) return;
    const int userEnd = NUSERS * DIM / 4;
    float4 v = (i < userEnd) ? ((const float4*)ue)[i]
                             : ((const float4*)ie)[i - userEnd];
    ((float4*)acc)[i] = v;
    ushort4 h;
    h.x = f32_to_bf16(v.x); h.y = f32_to_bf16(v.y);
    h.z = f32_to_bf16(v.z); h.w = f32_to_bf16(v.w);
    ((ushort4*)xb0)[i] = h;
}

// ---------------- CSR SpMM: one wave per row, SGPR edge loads, bf16 gather ---

// Edge list fetch is wave-uniform: force start/end into SGPRs via
// readfirstlane so packed[idx] selects s_load_dwordx2/x8 (scalar cache,
// no LDS-pipe bpermute broadcast). Per edge: ~2 SALU addr + 1 VMEM
// gather (global_load_ushort, 128B/wave, coalesced) + lshl + fmac.
// FINAL=0: y = bf16(s); acc += s       (layers 1,2; acc already holds x0+...)
// FINAL=1: acc = (acc + s) * 0.25      (layer 3)
template <int FINAL>
__global__ void __launch_bounds__(256) k_spmm_csr(
                           const int* __restrict__ rowptr, const int2* __restrict__ packed,
                           const unsigned short* __restrict__ xin,
                           unsigned short* __restrict__ y, float* __restrict__ acc) {
    int row  = blockIdx.x * (blockDim.x >> 6) + (threadIdx.x >> 6);
    int lane = threadIdx.x & 63;
    if (row >= NNODES) return;
    int start = __builtin_amdgcn_readfirstlane(rowptr[row]);
    int end   = __builtin_amdgcn_readfirstlane(rowptr[row + 1]);
    const unsigned short* __restrict__ xl = xin + lane;
    float s0 = 0.f, s1 = 0.f, s2 = 0.f, s3 = 0.f;
    int idx = start;
    for (; idx + 4 <= end; idx += 4) {
        int2 e0 = packed[idx + 0];          // contiguous SGPR loads (32B)
        int2 e1 = packed[idx + 1];
        int2 e2 = packed[idx + 2];
        int2 e3 = packed[idx + 3];
        float g0 = bf16_to_f32(xl[(size_t)e0.x << 6]);
        float g1 = bf16_to_f32(xl[(size_t)e1.x << 6]);
        float g2 = bf16_to_f32(xl[(size_t)e2.x << 6]);
        float g3 = bf16_to_f32(xl[(size_t)e3.x << 6]);
        s0 += __int_as_float(e0.y) * g0;
        s1 += __int_as_float(e1.y) * g1;
        s2 += __int_as_float(e2.y) * g2;
        s3 += __int_as_float(e3.y) * g3;
    }
    for (; idx < end; ++idx) {
        int2 e = packed[idx];
        s0 += __int_as_float(e.y) * bf16_to_f32(xl[(size_t)e.x << 6]);
    }
    float s = (s0 + s1) + (s2 + s3);
    size_t o = ((size_t)row << 6) + lane;
    if (FINAL) {
        acc[o] = (acc[o] + s) * 0.25f;
    } else {
        y[o] = f32_to_bf16(s);
        acc[o] += s;
    }
}

// ---------------- launch ----------------

extern "C" void kernel_launch(void* const* d_in, const int* in_sizes, int n_in,
                              void* d_out, int out_size, void* d_ws, size_t ws_size,
                              hipStream_t stream) {
    const float* ue   = (const float*)d_in[0];
    const float* ie   = (const float*)d_in[1];
    const int*   rows = (const int*)d_in[2];
    const int*   cols = (const int*)d_in[3];
    const float* vals = (const float*)d_in[4];
    float* acc = (float*)d_out;

    const size_t embN = (size_t)NNODES * DIM;            // 19.2M elements
    char* p = (char*)d_ws;
    unsigned short* xb0 = (unsigned short*)p;  p += embN * 2;                 // 38.4 MB
    unsigned short* xb1 = (unsigned short*)p;  p += embN * 2;                 // 38.4 MB
    unsigned short* xb2 = (unsigned short*)p;  p += embN * 2;                 // 38.4 MB
    int*   rowptr = (int*)p;              p += (size_t)(CNT_PAD + 16) * 4;    // 1.2 MB
    int*   cnt    = (int*)p;              p += (size_t)(CNT_PAD + 16) * 4;    // 1.2 MB
    int*   part   = (int*)p;              p += 512 * 4;
    int*   poff   = (int*)p;              p += 512 * 4;
    int*   gcur   = (int*)p;              p += 512 * 4;
    int2*  staged = (int2*)p;             p += (size_t)NNZ_CNT * 8;           // 32 MB
    int2*  packed = (int2*)p;             p += (size_t)NNZ_CNT * 8;           // 32 MB

    const int edge_blocks = (NNZ_CNT + 255) / 256;
    const int row_blocks  = (NNODES + 3) / 4;             // 4 waves/block
    const int bucketA_blocks = (NNZ_CNT + EPB - 1) / EPB; // 489
    const int vec_blocks = (NNODES * DIM / 4 + 255) / 256;

    // --- rowptr ---
    hipMemsetAsync(cnt, 0, (size_t)(CNT_PAD + 16) * 4, stream);
    k_hist<<<edge_blocks, 256, 0, stream>>>(rows, cnt);
    k_partial<<<NCHUNKS, 256, 0, stream>>>(cnt, part);
    k_scanpartial<<<1, 512, 0, stream>>>(part, poff);
    k_scan3<<<NCHUNKS, 256, 0, stream>>>(cnt, poff, rowptr);

    // --- bucket sort: COO -> staged (bucket-major) -> packed (row-major) ---
    k_initcur<<<2, 256, 0, stream>>>(rowptr, gcur);
    k_bucketA<<<bucketA_blocks, 256, 0, stream>>>(rows, cols, vals, gcur, staged);
    k_bucketB<<<NB, 1024, 0, stream>>>(rowptr, staged, packed);

    // --- x0: bf16 copy + fp32 acc init ---
    k_init0<<<vec_blocks, 256, 0, stream>>>(ue, ie, xb0, acc);

    // --- 3 layers, acc fused, /4 fused into last ---
    k_spmm_csr<0><<<row_blocks, 256, 0, stream>>>(rowptr, packed, xb0, xb1, acc);
    k_spmm_csr<0><<<row_blocks, 256, 0, stream>>>(rowptr, packed, xb1, xb2, acc);
    k_spmm_csr<1><<<row_blocks, 256, 0, stream>>>(rowptr, packed, xb2, (unsigned short*)nullptr, acc);
}

// Round 2
// 816.550 us; speedup vs baseline: 1.0730x; 1.0646x over previous
//
#include <hip/hip_runtime.h>

// LightGCN: out = (x0 + A x0 + A^2 x0 + A^3 x0) / 4, COO 4M nnz, N=300k, D=64.
// R5: inter-layer activations bf16 (row=128B); fp32 accumulation.
// R6: SpMM edge records via wave-uniform SGPR loads.
// R7a: k_hist (4M device-scope atomics, 125MB coherence-point RMW traffic,
//      154us) + 3 scan kernels DELETED. Row histogram/scan now computed
//      inside the bucket pipeline: per-bucket totals via LDS hist (k_bhist),
//      1-block bucket scan (k_bscan), and per-row count+scan fused into
//      bucketB (LDS atomics + 1024-wide LDS scan -> writes rowptr slice).
// R7b: spmm software-pipelined: 8-edge chunks, next chunk's records
//      prefetched (s_load) while current chunk's 8 gathers are in flight;
//      masked tail keeps all 8 gathers issued in parallel. Removes the
//      record-load latency from the per-chunk critical path.

#define NUSERS 200000
#define NITEMS 100000
#define NNODES 300000
#define DIM 64
#define NNZ_CNT 4000000

#define BSHIFT 10
#define BROWS  (1 << BSHIFT)                               // 1024 rows per bucket
#define NB     ((NNODES + BROWS - 1) >> BSHIFT)            // 293 buckets
#define EPB    8192                                        // edges per block (hist/A)

// ---------------- bf16 helpers (RNE) ----------------

__device__ __forceinline__ unsigned short f32_to_bf16(float f) {
    unsigned u = __float_as_uint(f);
    u += 0x7FFFu + ((u >> 16) & 1u);
    return (unsigned short)(u >> 16);
}
__device__ __forceinline__ float bf16_to_f32(unsigned short h) {
    return __uint_as_float(((unsigned)h) << 16);
}

// ---------------- bucket totals: LDS hist, few global atomics ----------------

__global__ void __launch_bounds__(256) k_bhist(const int* __restrict__ rows,
                                               int* __restrict__ bcnt) {
    __shared__ int hist[NB];
    int t = threadIdx.x;
    int e0 = blockIdx.x * EPB;
    for (int i = t; i < NB; i += 256) hist[i] = 0;
    __syncthreads();
    for (int k = 0; k < EPB / 256; ++k) {
        int e = e0 + k * 256 + t;
        if (e < NNZ_CNT) atomicAdd(&hist[rows[e] >> BSHIFT], 1);
    }
    __syncthreads();
    for (int i = t; i < NB; i += 256) {
        int h = hist[i];
        if (h) atomicAdd(&bcnt[i], h);
    }
}

// 1 block, 512 threads: exclusive scan of bucket counts -> bases + cursors.
__global__ void k_bscan(const int* __restrict__ bcnt, int* __restrict__ bbase,
                        int* __restrict__ gcur) {
    int t = threadIdx.x;
    int v = (t < NB) ? bcnt[t] : 0;
    __shared__ int lds[512];
    lds[t] = v; __syncthreads();
    for (int d = 1; d < 512; d <<= 1) {
        int cur = lds[t];
        int add = (t >= d) ? lds[t - d] : 0;
        __syncthreads();
        lds[t] = cur + add;
        __syncthreads();
    }
    if (t < NB) {
        int e = lds[t] - v;          // exclusive
        bbase[t] = e;
        gcur[t]  = e;
    }
    if (t == 511) bbase[NB] = lds[511];   // == NNZ
}

// ---------------- Phase A: bucket staging (LDS-binned) ----------------

__global__ void __launch_bounds__(256) k_bucketA(
        const int* __restrict__ rows, const int* __restrict__ cols,
        const float* __restrict__ vals, int* __restrict__ gcursor,
        int2* __restrict__ staged) {
    __shared__ int hist[NB];
    __shared__ int lbase[NB];
    __shared__ int lcur[NB];
    int t = threadIdx.x;
    int e0 = blockIdx.x * EPB;
    for (int i = t; i < NB; i += 256) { hist[i] = 0; lcur[i] = 0; }
    __syncthreads();
    // pass 1: local histogram
    for (int k = 0; k < EPB / 256; ++k) {
        int e = e0 + k * 256 + t;
        if (e < NNZ_CNT) atomicAdd(&hist[rows[e] >> BSHIFT], 1);
    }
    __syncthreads();
    // reserve contiguous ranges per bucket
    for (int i = t; i < NB; i += 256) {
        int h = hist[i];
        lbase[i] = h ? atomicAdd(&gcursor[i], h) : 0;
    }
    __syncthreads();
    // pass 2: place edges
    for (int k = 0; k < EPB / 256; ++k) {
        int e = e0 + k * 256 + t;
        if (e >= NNZ_CNT) continue;
        int r = rows[e];
        int b = r >> BSHIFT;
        int p = lbase[b] + atomicAdd(&lcur[b], 1);
        int2 rec;
        rec.x = ((r & (BROWS - 1)) << 19) | cols[e];   // rel_row[10] | col[19]
        rec.y = __float_as_int(vals[e]);
        staged[p] = rec;
    }
}

// ---------------- Phase B: per-bucket count + scan + row sort ----------------
// Fuses the old per-row histogram/scan: counts rel-rows from staged (4B reads,
// second pass L2-hot), 1024-wide LDS scan -> rowptr slice + scatter cursors.

__global__ void __launch_bounds__(1024) k_bucketB(
        const int* __restrict__ bbase, const int2* __restrict__ staged,
        int2* __restrict__ packed, int* __restrict__ rowptr) {
    __shared__ int rcnt[BROWS];
    __shared__ int cur[BROWS];
    int b = blockIdx.x;
    int t = threadIdx.x;
    int r0 = b << BSHIFT;
    int r1 = min(r0 + BROWS, NNODES);
    int nrows = r1 - r0;
    rcnt[t] = 0;
    __syncthreads();
    int start = bbase[b];
    int end   = bbase[b + 1];
    // pass 1: per-row counts (load only .x of each record)
    const int* sx = (const int*)staged;
    for (int idx = start + t; idx < end; idx += 1024)
        atomicAdd(&rcnt[((unsigned)sx[idx << 1]) >> 19], 1);
    __syncthreads();
    int v = rcnt[t];
    // in-place inclusive scan (Hillis-Steele)
    for (int d = 1; d < 1024; d <<= 1) {
        int c = rcnt[t];
        int a = (t >= d) ? rcnt[t - d] : 0;
        __syncthreads();
        rcnt[t] = c + a;
        __syncthreads();
    }
    int excl = rcnt[t] - v;
    cur[t] = start + excl;
    if (t < nrows) rowptr[r0 + t] = start + excl;
    if (b == NB - 1 && t == 0) rowptr[NNODES] = end;   // == NNZ
    __syncthreads();
    // pass 2: scatter to row-major packed
    for (int idx = start + t; idx < end; idx += 1024) {
        int2 rec = staged[idx];
        int rel = ((unsigned)rec.x) >> 19;
        int col = rec.x & 0x7FFFF;
        int pos = atomicAdd(&cur[rel], 1);
        int2 out; out.x = col; out.y = rec.y;
        packed[pos] = out;
    }
}

// ---------------- x0 -> bf16 + acc init ----------------

__global__ void k_init0(const float* __restrict__ ue, const float* __restrict__ ie,
                        unsigned short* __restrict__ xb0, float* __restrict__ acc) {
    int i = blockIdx.x * blockDim.x + threadIdx.x;      // float4 index
    const int total = NNODES * DIM / 4;
    if (i >= total) return;
    const int userEnd = NUSERS * DIM / 4;
    float4 v = (i < userEnd) ? ((const float4*)ue)[i]
                             : ((const float4*)ie)[i - userEnd];
    ((float4*)acc)[i] = v;
    ushort4 h;
    h.x = f32_to_bf16(v.x); h.y = f32_to_bf16(v.y);
    h.z = f32_to_bf16(v.z); h.w = f32_to_bf16(v.w);
    ((ushort4*)xb0)[i] = h;
}

// ---------------- CSR SpMM: one wave/row, pipelined SGPR records ----------------

// Chunks of 8 edges. Records for chunk i+1 are prefetched (wave-uniform ->
// s_load) while chunk i's 8 gathers are outstanding, so the per-chunk
// critical path is a single gather latency. Tail chunks clamp the record
// index (any in-range address) and zero the value via uniform mask.
// FINAL=0: y = bf16(s); acc += s       (layers 1,2)
// FINAL=1: acc = (acc + s) * 0.25      (layer 3)
template <int FINAL>
__global__ void __launch_bounds__(256) k_spmm_csr(
                           const int* __restrict__ rowptr, const int2* __restrict__ packed,
                           const unsigned short* __restrict__ xin,
                           unsigned short* __restrict__ y, float* __restrict__ acc) {
    int row  = blockIdx.x * (blockDim.x >> 6) + (threadIdx.x >> 6);
    int lane = threadIdx.x & 63;
    if (row >= NNODES) return;
    int start = __builtin_amdgcn_readfirstlane(rowptr[row]);
    int end   = __builtin_amdgcn_readfirstlane(rowptr[row + 1]);
    const unsigned short* __restrict__ xl = xin + lane;
    float s[8];
    #pragma unroll
    for (int j = 0; j < 8; ++j) s[j] = 0.f;

    if (start < end) {
        int2 e[8];
        #pragma unroll
        for (int j = 0; j < 8; ++j) {
            int k = start + j;
            e[j] = packed[(k < end) ? k : start];
        }
        for (int base = start; base < end; base += 8) {
            int nb = base + 8;
            int2 en[8];
            #pragma unroll
            for (int j = 0; j < 8; ++j) {          // prefetch next chunk
                int k = nb + j;
                en[j] = packed[(k < end) ? k : start];
            }
            #pragma unroll
            for (int j = 0; j < 8; ++j) {          // consume current chunk
                bool m = (base + j) < end;
                float g = bf16_to_f32(xl[(size_t)e[j].x << 6]);
                float v = m ? __int_as_float(e[j].y) : 0.0f;
                s[j] += v * g;
            }
            #pragma unroll
            for (int j = 0; j < 8; ++j) e[j] = en[j];
        }
    }
    float t0 = (s[0] + s[1]) + (s[2] + s[3]);
    float t1 = (s[4] + s[5]) + (s[6] + s[7]);
    float ssum = t0 + t1;
    size_t o = ((size_t)row << 6) + lane;
    if (FINAL) {
        acc[o] = (acc[o] + ssum) * 0.25f;
    } else {
        y[o] = f32_to_bf16(ssum);
        acc[o] += ssum;
    }
}

// ---------------- launch ----------------

extern "C" void kernel_launch(void* const* d_in, const int* in_sizes, int n_in,
                              void* d_out, int out_size, void* d_ws, size_t ws_size,
                              hipStream_t stream) {
    const float* ue   = (const float*)d_in[0];
    const float* ie   = (const float*)d_in[1];
    const int*   rows = (const int*)d_in[2];
    const int*   cols = (const int*)d_in[3];
    const float* vals = (const float*)d_in[4];
    float* acc = (float*)d_out;

    const size_t embN = (size_t)NNODES * DIM;            // 19.2M elements
    char* p = (char*)d_ws;
    unsigned short* xb0 = (unsigned short*)p;  p += embN * 2;                 // 38.4 MB
    unsigned short* xb1 = (unsigned short*)p;  p += embN * 2;                 // 38.4 MB
    unsigned short* xb2 = (unsigned short*)p;  p += embN * 2;                 // 38.4 MB
    int*   rowptr = (int*)p;              p += (size_t)(NNODES + 16) * 4;     // 1.2 MB
    int*   bcnt   = (int*)p;              p += 512 * 4;
    int*   bbase  = (int*)p;              p += 512 * 4;
    int*   gcur   = (int*)p;              p += 512 * 4;
    int2*  staged = (int2*)p;             p += (size_t)NNZ_CNT * 8;           // 32 MB
    int2*  packed = (int2*)p;             p += (size_t)NNZ_CNT * 8;           // 32 MB

    const int row_blocks  = (NNODES + 3) / 4;             // 4 waves/block
    const int edge_hblocks = (NNZ_CNT + EPB - 1) / EPB;   // 489
    const int vec_blocks = (NNODES * DIM / 4 + 255) / 256;

    // --- bucket totals + bases (replaces per-row hist + 3-kernel scan) ---
    hipMemsetAsync(bcnt, 0, 512 * 4, stream);
    k_bhist<<<edge_hblocks, 256, 0, stream>>>(rows, bcnt);
    k_bscan<<<1, 512, 0, stream>>>(bcnt, bbase, gcur);

    // --- bucket sort: COO -> staged (bucket-major) -> packed (row-major) ---
    // bucketB also derives rowptr (per-row count + LDS scan).
    k_bucketA<<<edge_hblocks, 256, 0, stream>>>(rows, cols, vals, gcur, staged);
    k_bucketB<<<NB, 1024, 0, stream>>>(bbase, staged, packed, rowptr);

    // --- x0: bf16 copy + fp32 acc init ---
    k_init0<<<vec_blocks, 256, 0, stream>>>(ue, ie, xb0, acc);

    // --- 3 layers, acc fused, /4 fused into last ---
    k_spmm_csr<0><<<row_blocks, 256, 0, stream>>>(rowptr, packed, xb0, xb1, acc);
    k_spmm_csr<0><<<row_blocks, 256, 0, stream>>>(rowptr, packed, xb1, xb2, acc);
    k_spmm_csr<1><<<row_blocks, 256, 0, stream>>>(rowptr, packed, xb2, (unsigned short*)nullptr, acc);
}

// Round 3
// 722.643 us; speedup vs baseline: 1.2124x; 1.1300x over previous
//
#include <hip/hip_runtime.h>

// LightGCN: out = (x0 + A x0 + A^2 x0 + A^3 x0) / 4, COO 4M nnz, N=300k, D=64.
// R5: inter-layer activations bf16 (row=128B); R6: SGPR edge records.
// R7: hist/scan kernels folded into bucket pipeline (bhist/bscan/bucketB).
// R8a: fp32 acc array DELETED. Layers 1-2 write only bf16 y (no 77MB acc
//      read + 77MB write per layer). Final layer fuses the mean:
//      out = (x0_fp32 + bf16(x1) + bf16(x2) + s3)/4, reading xb1/xb2 rows
//      as streaming loads. Cuts ~460MB of L3-churning stream traffic so
//      the 38.4MB gather table stays L3-resident (gathers were missing to
//      HBM at random-128B efficiency ~2.5TB/s -- the real spmm wall).
// R8b: R7's 8-deep "prefetch" reverted (SMEM drains at lgkmcnt(0), the
//      prefetch serialized with the consume and added SALU + 15MB FETCH).
//      Inner loop back to the flat 4-unroll SGPR form.

#define NUSERS 200000
#define NITEMS 100000
#define NNODES 300000
#define DIM 64
#define NNZ_CNT 4000000

#define BSHIFT 10
#define BROWS  (1 << BSHIFT)                               // 1024 rows per bucket
#define NB     ((NNODES + BROWS - 1) >> BSHIFT)            // 293 buckets
#define EPB    8192                                        // edges per block (hist/A)

// ---------------- bf16 helpers (RNE) ----------------

__device__ __forceinline__ unsigned short f32_to_bf16(float f) {
    unsigned u = __float_as_uint(f);
    u += 0x7FFFu + ((u >> 16) & 1u);
    return (unsigned short)(u >> 16);
}
__device__ __forceinline__ float bf16_to_f32(unsigned short h) {
    return __uint_as_float(((unsigned)h) << 16);
}

// ---------------- bucket totals: LDS hist, few global atomics ----------------

__global__ void __launch_bounds__(256) k_bhist(const int* __restrict__ rows,
                                               int* __restrict__ bcnt) {
    __shared__ int hist[NB];
    int t = threadIdx.x;
    int e0 = blockIdx.x * EPB;
    for (int i = t; i < NB; i += 256) hist[i] = 0;
    __syncthreads();
    for (int k = 0; k < EPB / 256; ++k) {
        int e = e0 + k * 256 + t;
        if (e < NNZ_CNT) atomicAdd(&hist[rows[e] >> BSHIFT], 1);
    }
    __syncthreads();
    for (int i = t; i < NB; i += 256) {
        int h = hist[i];
        if (h) atomicAdd(&bcnt[i], h);
    }
}

// 1 block, 512 threads: exclusive scan of bucket counts -> bases + cursors.
__global__ void k_bscan(const int* __restrict__ bcnt, int* __restrict__ bbase,
                        int* __restrict__ gcur) {
    int t = threadIdx.x;
    int v = (t < NB) ? bcnt[t] : 0;
    __shared__ int lds[512];
    lds[t] = v; __syncthreads();
    for (int d = 1; d < 512; d <<= 1) {
        int cur = lds[t];
        int add = (t >= d) ? lds[t - d] : 0;
        __syncthreads();
        lds[t] = cur + add;
        __syncthreads();
    }
    if (t < NB) {
        int e = lds[t] - v;          // exclusive
        bbase[t] = e;
        gcur[t]  = e;
    }
    if (t == 511) bbase[NB] = lds[511];   // == NNZ
}

// ---------------- Phase A: bucket staging (LDS-binned) ----------------

__global__ void __launch_bounds__(256) k_bucketA(
        const int* __restrict__ rows, const int* __restrict__ cols,
        const float* __restrict__ vals, int* __restrict__ gcursor,
        int2* __restrict__ staged) {
    __shared__ int hist[NB];
    __shared__ int lbase[NB];
    __shared__ int lcur[NB];
    int t = threadIdx.x;
    int e0 = blockIdx.x * EPB;
    for (int i = t; i < NB; i += 256) { hist[i] = 0; lcur[i] = 0; }
    __syncthreads();
    // pass 1: local histogram
    for (int k = 0; k < EPB / 256; ++k) {
        int e = e0 + k * 256 + t;
        if (e < NNZ_CNT) atomicAdd(&hist[rows[e] >> BSHIFT], 1);
    }
    __syncthreads();
    // reserve contiguous ranges per bucket
    for (int i = t; i < NB; i += 256) {
        int h = hist[i];
        lbase[i] = h ? atomicAdd(&gcursor[i], h) : 0;
    }
    __syncthreads();
    // pass 2: place edges
    for (int k = 0; k < EPB / 256; ++k) {
        int e = e0 + k * 256 + t;
        if (e >= NNZ_CNT) continue;
        int r = rows[e];
        int b = r >> BSHIFT;
        int p = lbase[b] + atomicAdd(&lcur[b], 1);
        int2 rec;
        rec.x = ((r & (BROWS - 1)) << 19) | cols[e];   // rel_row[10] | col[19]
        rec.y = __float_as_int(vals[e]);
        staged[p] = rec;
    }
}

// ---------------- Phase B: per-bucket count + scan + row sort ----------------

__global__ void __launch_bounds__(1024) k_bucketB(
        const int* __restrict__ bbase, const int2* __restrict__ staged,
        int2* __restrict__ packed, int* __restrict__ rowptr) {
    __shared__ int rcnt[BROWS];
    __shared__ int cur[BROWS];
    int b = blockIdx.x;
    int t = threadIdx.x;
    int r0 = b << BSHIFT;
    int r1 = min(r0 + BROWS, NNODES);
    int nrows = r1 - r0;
    rcnt[t] = 0;
    __syncthreads();
    int start = bbase[b];
    int end   = bbase[b + 1];
    // pass 1: per-row counts (load only .x of each record)
    const int* sx = (const int*)staged;
    for (int idx = start + t; idx < end; idx += 1024)
        atomicAdd(&rcnt[((unsigned)sx[idx << 1]) >> 19], 1);
    __syncthreads();
    int v = rcnt[t];
    // in-place inclusive scan (Hillis-Steele)
    for (int d = 1; d < 1024; d <<= 1) {
        int c = rcnt[t];
        int a = (t >= d) ? rcnt[t - d] : 0;
        __syncthreads();
        rcnt[t] = c + a;
        __syncthreads();
    }
    int excl = rcnt[t] - v;
    cur[t] = start + excl;
    if (t < nrows) rowptr[r0 + t] = start + excl;
    if (b == NB - 1 && t == 0) rowptr[NNODES] = end;   // == NNZ
    __syncthreads();
    // pass 2: scatter to row-major packed
    for (int idx = start + t; idx < end; idx += 1024) {
        int2 rec = staged[idx];
        int rel = ((unsigned)rec.x) >> 19;
        int col = rec.x & 0x7FFFF;
        int pos = atomicAdd(&cur[rel], 1);
        int2 out; out.x = col; out.y = rec.y;
        packed[pos] = out;
    }
}

// ---------------- x0 -> bf16 ----------------

__global__ void k_init0(const float* __restrict__ ue, const float* __restrict__ ie,
                        unsigned short* __restrict__ xb0) {
    int i = blockIdx.x * blockDim.x + threadIdx.x;      // float4 index
    const int total = NNODES * DIM / 4;
    if (i >= total) return;
    const int userEnd = NUSERS * DIM / 4;
    float4 v = (i < userEnd) ? ((const float4*)ue)[i]
                             : ((const float4*)ie)[i - userEnd];
    ushort4 h;
    h.x = f32_to_bf16(v.x); h.y = f32_to_bf16(v.y);
    h.z = f32_to_bf16(v.z); h.w = f32_to_bf16(v.w);
    ((ushort4*)xb0)[i] = h;
}

// ---------------- CSR SpMM: one wave/row, SGPR edge records ----------------

// FINAL=0: y = bf16(s)                      (layers 1,2 -- write-only epilogue)
// FINAL=1: out = (x0 + x1 + x2 + s) * 0.25  (x0 fp32 from ue/ie; x1,x2 bf16
//          streaming rows from xb1 (xprev) and xb2 (xin itself))
template <int FINAL>
__global__ void __launch_bounds__(256) k_spmm(
        const int* __restrict__ rowptr, const int2* __restrict__ packed,
        const unsigned short* __restrict__ xin,
        unsigned short* __restrict__ y,
        const unsigned short* __restrict__ xprev,
        const float* __restrict__ ue, const float* __restrict__ ie,
        float* __restrict__ out) {
    int row  = blockIdx.x * (blockDim.x >> 6) + (threadIdx.x >> 6);
    int lane = threadIdx.x & 63;
    if (row >= NNODES) return;
    int start = __builtin_amdgcn_readfirstlane(rowptr[row]);
    int end   = __builtin_amdgcn_readfirstlane(rowptr[row + 1]);
    const unsigned short* __restrict__ xl = xin + lane;
    float s0 = 0.f, s1 = 0.f, s2 = 0.f, s3 = 0.f;
    int idx = start;
    for (; idx + 4 <= end; idx += 4) {
        int2 e0 = packed[idx + 0];          // wave-uniform -> s_load
        int2 e1 = packed[idx + 1];
        int2 e2 = packed[idx + 2];
        int2 e3 = packed[idx + 3];
        float g0 = bf16_to_f32(xl[(size_t)e0.x << 6]);
        float g1 = bf16_to_f32(xl[(size_t)e1.x << 6]);
        float g2 = bf16_to_f32(xl[(size_t)e2.x << 6]);
        float g3 = bf16_to_f32(xl[(size_t)e3.x << 6]);
        s0 += __int_as_float(e0.y) * g0;
        s1 += __int_as_float(e1.y) * g1;
        s2 += __int_as_float(e2.y) * g2;
        s3 += __int_as_float(e3.y) * g3;
    }
    for (; idx < end; ++idx) {
        int2 e = packed[idx];
        s0 += __int_as_float(e.y) * bf16_to_f32(xl[(size_t)e.x << 6]);
    }
    float s = (s0 + s1) + (s2 + s3);
    size_t o = ((size_t)row << 6) + lane;
    if (FINAL) {
        float x0 = (row < NUSERS) ? ue[o] : ie[o - (size_t)NUSERS * DIM];
        float x1 = bf16_to_f32(xprev[o]);
        float x2 = bf16_to_f32(xin[o]);
        out[o] = (x0 + x1 + x2 + s) * 0.25f;
    } else {
        y[o] = f32_to_bf16(s);
    }
}

// ---------------- launch ----------------

extern "C" void kernel_launch(void* const* d_in, const int* in_sizes, int n_in,
                              void* d_out, int out_size, void* d_ws, size_t ws_size,
                              hipStream_t stream) {
    const float* ue   = (const float*)d_in[0];
    const float* ie   = (const float*)d_in[1];
    const int*   rows = (const int*)d_in[2];
    const int*   cols = (const int*)d_in[3];
    const float* vals = (const float*)d_in[4];
    float* out = (float*)d_out;

    const size_t embN = (size_t)NNODES * DIM;            // 19.2M elements
    char* p = (char*)d_ws;
    unsigned short* xb0 = (unsigned short*)p;  p += embN * 2;                 // 38.4 MB
    unsigned short* xb1 = (unsigned short*)p;  p += embN * 2;                 // 38.4 MB
    unsigned short* xb2 = (unsigned short*)p;  p += embN * 2;                 // 38.4 MB
    int*   rowptr = (int*)p;              p += (size_t)(NNODES + 16) * 4;     // 1.2 MB
    int*   bcnt   = (int*)p;              p += 512 * 4;
    int*   bbase  = (int*)p;              p += 512 * 4;
    int*   gcur   = (int*)p;              p += 512 * 4;
    int2*  staged = (int2*)p;             p += (size_t)NNZ_CNT * 8;           // 32 MB
    int2*  packed = (int2*)p;             p += (size_t)NNZ_CNT * 8;           // 32 MB

    const int row_blocks  = (NNODES + 3) / 4;             // 4 waves/block
    const int edge_hblocks = (NNZ_CNT + EPB - 1) / EPB;   // 489
    const int vec_blocks = (NNODES * DIM / 4 + 255) / 256;

    // --- bucket totals + bases ---
    hipMemsetAsync(bcnt, 0, 512 * 4, stream);
    k_bhist<<<edge_hblocks, 256, 0, stream>>>(rows, bcnt);
    k_bscan<<<1, 512, 0, stream>>>(bcnt, bbase, gcur);

    // --- bucket sort: COO -> staged (bucket-major) -> packed (row-major) ---
    k_bucketA<<<edge_hblocks, 256, 0, stream>>>(rows, cols, vals, gcur, staged);
    k_bucketB<<<NB, 1024, 0, stream>>>(bbase, staged, packed, rowptr);

    // --- x0 -> bf16 ---
    k_init0<<<vec_blocks, 256, 0, stream>>>(ue, ie, xb0);

    // --- 3 layers; mean fused into the last (reads x0 fp32 + x1,x2 bf16) ---
    k_spmm<0><<<row_blocks, 256, 0, stream>>>(rowptr, packed, xb0, xb1,
                                              (const unsigned short*)nullptr, ue, ie, (float*)nullptr);
    k_spmm<0><<<row_blocks, 256, 0, stream>>>(rowptr, packed, xb1, xb2,
                                              (const unsigned short*)nullptr, ue, ie, (float*)nullptr);
    k_spmm<1><<<row_blocks, 256, 0, stream>>>(rowptr, packed, xb2, (unsigned short*)nullptr,
                                              xb1, ue, ie, out);
}